// Round 1
// baseline (1017.468 us; speedup 1.0000x reference)
//
#include <hip/hip_runtime.h>
#include <math.h>

#define N_NODES 32768
#define E_DIM   512
#define H_HEADS 8
#define D_HEAD  64
#define NNZ_E   524288

// ---------------------------------------------------------------------------
// GEMM: out[m,n] = (sum_k x[m,k] * w[n,k] + bias[n]) * scale
// fp32 vector-ALU tiled GEMM. BM=128, BN=64, BK=16, 256 threads, 8x4 microtile.
// ---------------------------------------------------------------------------
__global__ __launch_bounds__(256) void gemm_xwT(
    const float* __restrict__ x, const float* __restrict__ w,
    const float* __restrict__ bias, float* __restrict__ out, float scale) {
  __shared__ float As[16][132];  // [k][m], +4 pad
  __shared__ float Bs[16][68];   // [k][n], +4 pad
  const int tid = threadIdx.x;
  const int bm = blockIdx.x * 128;
  const int bn = blockIdx.y * 64;
  const int ty = tid >> 4;   // 0..15 -> row group (8 rows each)
  const int tx = tid & 15;   // 0..15 -> col group (4 cols each)

  float acc[8][4];
#pragma unroll
  for (int i = 0; i < 8; ++i)
#pragma unroll
    for (int j = 0; j < 4; ++j) acc[i][j] = 0.f;

  for (int k0 = 0; k0 < E_DIM; k0 += 16) {
    // Stage A tile: 128 rows x 16 k = 512 float4, 2 per thread
#pragma unroll
    for (int i = 0; i < 2; ++i) {
      const int idx = tid * 2 + i;
      const int row = idx >> 2;
      const int kk = (idx & 3) << 2;
      const float4 v = *(const float4*)(x + (size_t)(bm + row) * E_DIM + k0 + kk);
      As[kk + 0][row] = v.x; As[kk + 1][row] = v.y;
      As[kk + 2][row] = v.z; As[kk + 3][row] = v.w;
    }
    // Stage B tile (w rows are the output-n dim): 64 x 16 = 256 float4, 1/thread
    {
      const int n = tid >> 2;
      const int kk = (tid & 3) << 2;
      const float4 v = *(const float4*)(w + (size_t)(bn + n) * E_DIM + k0 + kk);
      Bs[kk + 0][n] = v.x; Bs[kk + 1][n] = v.y;
      Bs[kk + 2][n] = v.z; Bs[kk + 3][n] = v.w;
    }
    __syncthreads();
#pragma unroll
    for (int kk = 0; kk < 16; ++kk) {
      float a[8], b[4];
#pragma unroll
      for (int i = 0; i < 8; ++i) a[i] = As[kk][ty * 8 + i];
#pragma unroll
      for (int j = 0; j < 4; ++j) b[j] = Bs[kk][tx * 4 + j];
#pragma unroll
      for (int i = 0; i < 8; ++i)
#pragma unroll
        for (int j = 0; j < 4; ++j) acc[i][j] = fmaf(a[i], b[j], acc[i][j]);
    }
    __syncthreads();
  }

#pragma unroll
  for (int i = 0; i < 8; ++i) {
    const int m = bm + ty * 8 + i;
    const int n = bn + tx * 4;
    float4 v;
    v.x = (acc[i][0] + bias[n + 0]) * scale;
    v.y = (acc[i][1] + bias[n + 1]) * scale;
    v.z = (acc[i][2] + bias[n + 2]) * scale;
    v.w = (acc[i][3] + bias[n + 3]) * scale;
    *(float4*)(out + (size_t)m * E_DIM + n) = v;
  }
}

// ---------------------------------------------------------------------------
// CSR row_start construction from sorted row_index.
// row_start[r] = first edge e with row_index[e] >= r;  row_start[N] = NNZ.
// ---------------------------------------------------------------------------
__global__ void build_row_start(const int* __restrict__ row_index,
                                int* __restrict__ row_start) {
  const int e = blockIdx.x * blockDim.x + threadIdx.x;
  if (e >= NNZ_E) return;
  const int r0 = row_index[e];
  const int r1 = (e + 1 < NNZ_E) ? row_index[e + 1] : N_NODES;
  if (e == 0)
    for (int r = 0; r <= r0; ++r) row_start[r] = 0;
  for (int r = r0 + 1; r <= r1; ++r) row_start[r] = e + 1;
}

// ---------------------------------------------------------------------------
// Edge stage: one block per query row (512 thr = 8 waves, wave h = head h).
// Online softmax over the row's contiguous edge segment; accumulates
// dist-weighted col_pos and weight sum; writes [feat3, avg_inv_dist].
// ---------------------------------------------------------------------------
__global__ __launch_bounds__(512) void edge_attn(
    const float* __restrict__ q, const float* __restrict__ kfull,
    const int* __restrict__ row_start, const int* __restrict__ col_index,
    const int* __restrict__ to_col, const float* __restrict__ att_bias,
    const float* __restrict__ dist, const float* __restrict__ pos,
    const float* __restrict__ col_pos, float* __restrict__ out) {
  const int r = blockIdx.x;
  const int h = threadIdx.x >> 6;
  const int lane = threadIdx.x & 63;
  const int start = row_start[r];
  const int end = row_start[r + 1];

  const float qv = q[(size_t)r * E_DIM + h * D_HEAD + lane];

  float m = -INFINITY, l = 0.f, accw = 0.f;
  float a0 = 0.f, a1 = 0.f, a2 = 0.f;

  // 1-deep software pipeline on the gathered k row (the long-latency load)
  int cn = 0, gn = 0;
  float kvn = 0.f;
  if (start < end) {
    cn = col_index[start];
    gn = to_col[cn];
    kvn = kfull[(size_t)gn * E_DIM + h * D_HEAD + lane];
  }

  for (int e = start; e < end; ++e) {
    const int c = cn;
    const float kv = kvn;
    if (e + 1 < end) {
      cn = col_index[e + 1];
      gn = to_col[cn];
      kvn = kfull[(size_t)gn * E_DIM + h * D_HEAD + lane];
    }
    float s = qv * kv;
#pragma unroll
    for (int off = 32; off > 0; off >>= 1) s += __shfl_xor(s, off);
    s += att_bias[(size_t)h * NNZ_E + e];

    const float dd = dist[e];
    const float w = (dd == 0.f) ? 0.f : 1.f / dd;

    const float nm = fmaxf(m, s);
    const float sc = __expf(m - nm);   // m=-inf first iter -> sc=0
    const float p = __expf(s - nm);
    m = nm;
    l = fmaf(l, sc, p);
    const float pw = p * w;
    accw = fmaf(accw, sc, pw);
    const float c0 = col_pos[c * 3 + 0];
    const float c1 = col_pos[c * 3 + 1];
    const float c2 = col_pos[c * 3 + 2];
    a0 = fmaf(a0, sc, pw * c0);
    a1 = fmaf(a1, sc, pw * c1);
    a2 = fmaf(a2, sc, pw * c2);
  }

  const float invz = (l > 0.f) ? 1.f / l : 0.f;
  const float avg = accw * invz;
  const float v0 = a0 * invz - avg * pos[r * 3 + 0];
  const float v1 = a1 * invz - avg * pos[r * 3 + 1];
  const float v2 = a2 * invz - avg * pos[r * 3 + 2];
  const float nrm = sqrtf(v0 * v0 + v1 * v1 + v2 * v2);
  const float invn = 1.f / fmaxf(nrm, 1e-12f);

  if (lane == 0) {
    float4 o;
    o.x = v0 * invn; o.y = v1 * invn; o.z = v2 * invn; o.w = avg;
    *(float4*)(out + (size_t)r * (H_HEADS * 4) + h * 4) = o;
  }
}

// ---------------------------------------------------------------------------
extern "C" void kernel_launch(void* const* d_in, const int* in_sizes, int n_in,
                              void* d_out, int out_size, void* d_ws,
                              size_t ws_size, hipStream_t stream) {
  const float* x        = (const float*)d_in[0];
  const int* row_index  = (const int*)d_in[1];
  const int* col_index  = (const int*)d_in[2];
  const int* to_col     = (const int*)d_in[3];
  const float* att_bias = (const float*)d_in[4];
  const float* dist     = (const float*)d_in[5];
  const float* pos      = (const float*)d_in[6];
  const float* col_pos  = (const float*)d_in[7];
  const float* q_w      = (const float*)d_in[8];
  const float* q_b      = (const float*)d_in[9];
  const float* k_w      = (const float*)d_in[10];
  const float* k_b      = (const float*)d_in[11];
  float* out = (float*)d_out;

  // Workspace layout: q [N*E f32] | kfull [N*E f32] | row_start [N+1 i32]
  float* q = (float*)d_ws;
  float* kfull = q + (size_t)N_NODES * E_DIM;
  int* row_start = (int*)(kfull + (size_t)N_NODES * E_DIM);

  dim3 gg(N_NODES / 128, E_DIM / 64);
  gemm_xwT<<<gg, 256, 0, stream>>>(x, q_w, q_b, q, 0.125f);   // 1/sqrt(64)
  gemm_xwT<<<gg, 256, 0, stream>>>(x, k_w, k_b, kfull, 1.0f);
  build_row_start<<<NNZ_E / 256, 256, 0, stream>>>(row_index, row_start);
  edge_attn<<<N_NODES, 512, 0, stream>>>(q, kfull, row_start, col_index,
                                         to_col, att_bias, dist, pos, col_pos,
                                         out);
}

// Round 2
// 732.464 us; speedup vs baseline: 1.3891x; 1.3891x over previous
//
#include <hip/hip_runtime.h>
#include <math.h>

#define N_NODES 32768
#define E_DIM   512
#define H_HEADS 8
#define D_HEAD  64
#define NNZ_E   524288

// ---------------------------------------------------------------------------
// GEMM: out[m,n] = (sum_k x[m,k] * w[n,k] + bias[n]) * scale
// fp32 vector-ALU tiled GEMM. BM=128, BN=128, BK=16, 256 threads, 8x8 microtile.
// ---------------------------------------------------------------------------
__global__ __launch_bounds__(256) void gemm_xwT(
    const float* __restrict__ x, const float* __restrict__ w,
    const float* __restrict__ bias, float* __restrict__ out, float scale) {
  __shared__ float As[16][132];  // [k][m], +4 pad (row = 528B, 16B-aligned)
  __shared__ float Bs[16][132];  // [k][n]
  const int tid = threadIdx.x;
  const int bm = blockIdx.x * 128;
  const int bn = blockIdx.y * 128;
  const int ty = tid >> 4;   // 0..15 -> 8-row group
  const int tx = tid & 15;   // 0..15 -> 8-col group

  float acc[8][8];
#pragma unroll
  for (int i = 0; i < 8; ++i)
#pragma unroll
    for (int j = 0; j < 8; ++j) acc[i][j] = 0.f;

  for (int k0 = 0; k0 < E_DIM; k0 += 16) {
    // A tile: 128 rows x 16 k = 512 float4, 2 per thread
#pragma unroll
    for (int i = 0; i < 2; ++i) {
      const int idx = tid + i * 256;
      const int row = idx >> 2;
      const int kk = (idx & 3) << 2;
      const float4 v = *(const float4*)(x + (size_t)(bm + row) * E_DIM + k0 + kk);
      As[kk + 0][row] = v.x; As[kk + 1][row] = v.y;
      As[kk + 2][row] = v.z; As[kk + 3][row] = v.w;
    }
    // B tile: 128 n x 16 k = 512 float4, 2 per thread
#pragma unroll
    for (int i = 0; i < 2; ++i) {
      const int idx = tid + i * 256;
      const int n = idx >> 2;
      const int kk = (idx & 3) << 2;
      const float4 v = *(const float4*)(w + (size_t)(bn + n) * E_DIM + k0 + kk);
      Bs[kk + 0][n] = v.x; Bs[kk + 1][n] = v.y;
      Bs[kk + 2][n] = v.z; Bs[kk + 3][n] = v.w;
    }
    __syncthreads();
#pragma unroll
    for (int kk = 0; kk < 16; ++kk) {
      float a[8], b[8];
      *(float4*)&a[0] = *(const float4*)&As[kk][ty * 8 + 0];
      *(float4*)&a[4] = *(const float4*)&As[kk][ty * 8 + 4];
      *(float4*)&b[0] = *(const float4*)&Bs[kk][tx * 8 + 0];
      *(float4*)&b[4] = *(const float4*)&Bs[kk][tx * 8 + 4];
#pragma unroll
      for (int i = 0; i < 8; ++i)
#pragma unroll
        for (int j = 0; j < 8; ++j) acc[i][j] = fmaf(a[i], b[j], acc[i][j]);
    }
    __syncthreads();
  }

#pragma unroll
  for (int i = 0; i < 8; ++i) {
    const int m = bm + ty * 8 + i;
    float* op = out + (size_t)m * E_DIM + bn + tx * 8;
    const float* bp = bias + bn + tx * 8;
    float4 v0, v1;
    v0.x = (acc[i][0] + bp[0]) * scale;
    v0.y = (acc[i][1] + bp[1]) * scale;
    v0.z = (acc[i][2] + bp[2]) * scale;
    v0.w = (acc[i][3] + bp[3]) * scale;
    v1.x = (acc[i][4] + bp[4]) * scale;
    v1.y = (acc[i][5] + bp[5]) * scale;
    v1.z = (acc[i][6] + bp[6]) * scale;
    v1.w = (acc[i][7] + bp[7]) * scale;
    *(float4*)(op + 0) = v0;
    *(float4*)(op + 4) = v1;
  }
}

// ---------------------------------------------------------------------------
// CSR row_start construction from sorted row_index.
// ---------------------------------------------------------------------------
__global__ void build_row_start(const int* __restrict__ row_index,
                                int* __restrict__ row_start) {
  const int e = blockIdx.x * blockDim.x + threadIdx.x;
  if (e >= NNZ_E) return;
  const int r0 = row_index[e];
  const int r1 = (e + 1 < NNZ_E) ? row_index[e + 1] : N_NODES;
  if (e == 0)
    for (int r = 0; r <= r0; ++r) row_start[r] = 0;
  for (int r = r0 + 1; r <= r1; ++r) row_start[r] = e + 1;
}

// ---------------------------------------------------------------------------
// Phase A: one wave per edge. Wave reads the edge's full q row and gathered
// k row (2 KB each, coalesced: lane i holds floats [8i, 8i+8)), computes all
// 8 head logits at once (8 fma/lane + 3-step shuffle within 8-lane groups),
// adds att_bias, writes logits[e][h].
// ---------------------------------------------------------------------------
__global__ __launch_bounds__(256) void edge_logits(
    const float* __restrict__ q, const float* __restrict__ kfull,
    const int* __restrict__ row_index, const int* __restrict__ col_index,
    const int* __restrict__ to_col, const float* __restrict__ att_bias,
    float* __restrict__ logits) {
  const int wave = threadIdx.x >> 6;           // 0..3
  const int lane = threadIdx.x & 63;
  const int e = blockIdx.x * 4 + wave;
  const int r = row_index[e];
  const int g = to_col[col_index[e]];

  const float* qp = q + (size_t)r * E_DIM + lane * 8;
  const float* kp = kfull + (size_t)g * E_DIM + lane * 8;
  const float4 q0 = *(const float4*)(qp + 0);
  const float4 q1 = *(const float4*)(qp + 4);
  const float4 k0 = *(const float4*)(kp + 0);
  const float4 k1 = *(const float4*)(kp + 4);

  float s = q0.x * k0.x;
  s = fmaf(q0.y, k0.y, s);
  s = fmaf(q0.z, k0.z, s);
  s = fmaf(q0.w, k0.w, s);
  s = fmaf(q1.x, k1.x, s);
  s = fmaf(q1.y, k1.y, s);
  s = fmaf(q1.z, k1.z, s);
  s = fmaf(q1.w, k1.w, s);
  s += __shfl_xor(s, 1);
  s += __shfl_xor(s, 2);
  s += __shfl_xor(s, 4);
  if ((lane & 7) == 0) {
    const int h = lane >> 3;
    logits[(size_t)e * H_HEADS + h] = s + att_bias[(size_t)h * NNZ_E + e];
  }
}

// ---------------------------------------------------------------------------
// Phase B: one wave per row. Lane (h = lane>>3, j = lane&7) runs an
// independent online-softmax accumulation for head h over edges start+j,
// start+j+8, ...; then a 3-step associative merge of (m,l,accw,a0..a2)
// across the 8-lane group; lane j==0 finalizes + writes float4.
// ---------------------------------------------------------------------------
__global__ __launch_bounds__(64) void row_featurize(
    const float* __restrict__ logits, const int* __restrict__ row_start,
    const int* __restrict__ col_index, const float* __restrict__ dist,
    const float* __restrict__ pos, const float* __restrict__ col_pos,
    float* __restrict__ out) {
  const int r = blockIdx.x;
  const int lane = threadIdx.x;
  const int h = lane >> 3;
  const int j = lane & 7;
  const int start = row_start[r];
  const int end = row_start[r + 1];

  float m = -INFINITY, l = 0.f, accw = 0.f, a0 = 0.f, a1 = 0.f, a2 = 0.f;

  for (int e = start + j; e < end; e += 8) {
    const float s = logits[(size_t)e * H_HEADS + h];
    const float dd = dist[e];
    const float w = (dd == 0.f) ? 0.f : 1.f / dd;
    const int c = col_index[e];
    const float nm = fmaxf(m, s);
    const float sc = __expf(m - nm);     // first iter: exp(-inf)=0, nm finite
    const float p = __expf(s - nm);
    m = nm;
    l = fmaf(l, sc, p);
    const float pw = p * w;
    accw = fmaf(accw, sc, pw);
    a0 = fmaf(a0, sc, pw * col_pos[c * 3 + 0]);
    a1 = fmaf(a1, sc, pw * col_pos[c * 3 + 1]);
    a2 = fmaf(a2, sc, pw * col_pos[c * 3 + 2]);
  }

  // merge softmax states across the 8-lane group (xor 1,2,4)
#pragma unroll
  for (int off = 1; off < 8; off <<= 1) {
    const float mo = __shfl_xor(m, off);
    const float lo = __shfl_xor(l, off);
    const float wo = __shfl_xor(accw, off);
    const float b0 = __shfl_xor(a0, off);
    const float b1 = __shfl_xor(a1, off);
    const float b2 = __shfl_xor(a2, off);
    const float nm = fmaxf(m, mo);
    // fmaxf(-80) clamp: if m==mo==-inf, m-nm = NaN -> fmaxf(NaN,-80) = -80
    const float s1 = __expf(fmaxf(m - nm, -80.f));
    const float s2 = __expf(fmaxf(mo - nm, -80.f));
    m = nm;
    l = l * s1 + lo * s2;
    accw = accw * s1 + wo * s2;
    a0 = a0 * s1 + b0 * s2;
    a1 = a1 * s1 + b1 * s2;
    a2 = a2 * s1 + b2 * s2;
  }

  if (j == 0) {
    const float invz = (l > 0.f) ? 1.f / l : 0.f;
    const float avg = accw * invz;
    const float v0 = a0 * invz - avg * pos[r * 3 + 0];
    const float v1 = a1 * invz - avg * pos[r * 3 + 1];
    const float v2 = a2 * invz - avg * pos[r * 3 + 2];
    const float nrm = sqrtf(v0 * v0 + v1 * v1 + v2 * v2);
    const float invn = 1.f / fmaxf(nrm, 1e-12f);
    float4 o;
    o.x = v0 * invn; o.y = v1 * invn; o.z = v2 * invn; o.w = avg;
    *(float4*)(out + (size_t)r * (H_HEADS * 4) + h * 4) = o;
  }
}

// ---------------------------------------------------------------------------
extern "C" void kernel_launch(void* const* d_in, const int* in_sizes, int n_in,
                              void* d_out, int out_size, void* d_ws,
                              size_t ws_size, hipStream_t stream) {
  const float* x        = (const float*)d_in[0];
  const int* row_index  = (const int*)d_in[1];
  const int* col_index  = (const int*)d_in[2];
  const int* to_col     = (const int*)d_in[3];
  const float* att_bias = (const float*)d_in[4];
  const float* dist     = (const float*)d_in[5];
  const float* pos      = (const float*)d_in[6];
  const float* col_pos  = (const float*)d_in[7];
  const float* q_w      = (const float*)d_in[8];
  const float* q_b      = (const float*)d_in[9];
  const float* k_w      = (const float*)d_in[10];
  const float* k_b      = (const float*)d_in[11];
  float* out = (float*)d_out;

  // ws: q [N*E] | kfull [N*E] | logits [NNZ*H] | row_start [N+1]
  float* q = (float*)d_ws;
  float* kfull = q + (size_t)N_NODES * E_DIM;
  float* logits = kfull + (size_t)N_NODES * E_DIM;
  int* row_start = (int*)(logits + (size_t)NNZ_E * H_HEADS);

  dim3 gg(N_NODES / 128, E_DIM / 128);
  gemm_xwT<<<gg, 256, 0, stream>>>(x, q_w, q_b, q, 0.125f);   // 1/sqrt(64)
  gemm_xwT<<<gg, 256, 0, stream>>>(x, k_w, k_b, kfull, 1.0f);
  build_row_start<<<NNZ_E / 256, 256, 0, stream>>>(row_index, row_start);
  edge_logits<<<NNZ_E / 4, 256, 0, stream>>>(q, kfull, row_index, col_index,
                                             to_col, att_bias, logits);
  row_featurize<<<N_NODES, 64, 0, stream>>>(logits, row_start, col_index,
                                            dist, pos, col_pos, out);
}

// Round 3
// 695.703 us; speedup vs baseline: 1.4625x; 1.0528x over previous
//
#include <hip/hip_runtime.h>
#include <math.h>

#define N_NODES 32768
#define E_DIM   512
#define H_HEADS 8
#define D_HEAD  64
#define NNZ_E   524288

// ---------------------------------------------------------------------------
// Fused q/k projection: blockIdx.z selects (q_w,q_b,scale=1/8 -> qout) or
// (k_w,k_b,scale=1 -> kout).  out[m,n] = (sum_k x[m,k]*w[n,k] + b[n])*scale
// BM=BN=128, BK=16, 256 threads, 8x8 microtile.
// Wave-level thread map gives 8 distinct ty x 8 distinct tx per wave:
// both LDS fragment reads are 8 addrs @ stride 32B = 2-way/bank = conflict-free.
// Register prefetch of next global tile overlaps the FMA loop.
// ---------------------------------------------------------------------------
__global__ __launch_bounds__(256, 2) void gemm_qk(
    const float* __restrict__ x, const float* __restrict__ q_w,
    const float* __restrict__ q_b, const float* __restrict__ k_w,
    const float* __restrict__ k_b, float* __restrict__ qout,
    float* __restrict__ kout) {
  __shared__ float As[16][132];  // [k][m], 132 = 128+4 (shift 4 banks per k)
  __shared__ float Bs[16][132];  // [k][n]
  const int tid = threadIdx.x;
  const bool is_q = (blockIdx.z == 0);
  const float* __restrict__ w = is_q ? q_w : k_w;
  const float* __restrict__ bias = is_q ? q_b : k_b;
  float* __restrict__ out = is_q ? qout : kout;
  const float scale = is_q ? 0.125f : 1.0f;

  const int bm = blockIdx.x * 128;
  const int bn = blockIdx.y * 128;
  const int wv = tid >> 6;        // wave 0..3
  const int lm = (tid >> 3) & 7;
  const int ln = tid & 7;
  const int ty = ((wv & 1) << 3) | lm;   // 0..15
  const int tx = ((wv >> 1) << 3) | ln;  // 0..15

  // global-load addressing: idx in [0,512) -> row idx>>2, float4-slot idx&3
  const float* __restrict__ xa = x + (size_t)bm * E_DIM;
  const float* __restrict__ wb = w + (size_t)bn * E_DIM;
  const int r0 = tid >> 2, c0 = (tid & 3) << 2;          // idx0 = tid
  const int r1 = 64 + r0;                                 // idx1 = tid+256

  float acc[8][8];
#pragma unroll
  for (int i = 0; i < 8; ++i)
#pragma unroll
    for (int j = 0; j < 8; ++j) acc[i][j] = 0.f;

  float4 pa0, pa1, pb0, pb1;
  // prologue: load tile 0
  pa0 = *(const float4*)(xa + (size_t)r0 * E_DIM + c0);
  pa1 = *(const float4*)(xa + (size_t)r1 * E_DIM + c0);
  pb0 = *(const float4*)(wb + (size_t)r0 * E_DIM + c0);
  pb1 = *(const float4*)(wb + (size_t)r1 * E_DIM + c0);

#define STORE_TILES()                                                  \
  {                                                                    \
    As[c0 + 0][r0] = pa0.x; As[c0 + 1][r0] = pa0.y;                    \
    As[c0 + 2][r0] = pa0.z; As[c0 + 3][r0] = pa0.w;                    \
    As[c0 + 0][r1] = pa1.x; As[c0 + 1][r1] = pa1.y;                    \
    As[c0 + 2][r1] = pa1.z; As[c0 + 3][r1] = pa1.w;                    \
    Bs[c0 + 0][r0] = pb0.x; Bs[c0 + 1][r0] = pb0.y;                    \
    Bs[c0 + 2][r0] = pb0.z; Bs[c0 + 3][r0] = pb0.w;                    \
    Bs[c0 + 0][r1] = pb1.x; Bs[c0 + 1][r1] = pb1.y;                    \
    Bs[c0 + 2][r1] = pb1.z; Bs[c0 + 3][r1] = pb1.w;                    \
  }

#define COMPUTE_TILE()                                                 \
  _Pragma("unroll") for (int kk = 0; kk < 16; ++kk) {                  \
    float a[8], b[8];                                                  \
    *(float4*)&a[0] = *(const float4*)&As[kk][ty * 8 + 0];             \
    *(float4*)&a[4] = *(const float4*)&As[kk][ty * 8 + 4];             \
    *(float4*)&b[0] = *(const float4*)&Bs[kk][tx * 8 + 0];             \
    *(float4*)&b[4] = *(const float4*)&Bs[kk][tx * 8 + 4];             \
    _Pragma("unroll") for (int i = 0; i < 8; ++i)                      \
        _Pragma("unroll") for (int j = 0; j < 8; ++j)                  \
            acc[i][j] = fmaf(a[i], b[j], acc[i][j]);                   \
  }

  STORE_TILES();
  __syncthreads();

  for (int k0 = 16; k0 < E_DIM; k0 += 16) {
    // issue next-tile loads; they stay in flight across the FMA loop
    pa0 = *(const float4*)(xa + (size_t)r0 * E_DIM + k0 + c0);
    pa1 = *(const float4*)(xa + (size_t)r1 * E_DIM + k0 + c0);
    pb0 = *(const float4*)(wb + (size_t)r0 * E_DIM + k0 + c0);
    pb1 = *(const float4*)(wb + (size_t)r1 * E_DIM + k0 + c0);
    COMPUTE_TILE();
    __syncthreads();
    STORE_TILES();
    __syncthreads();
  }
  COMPUTE_TILE();

#pragma unroll
  for (int i = 0; i < 8; ++i) {
    const int m = bm + ty * 8 + i;
    float* op = out + (size_t)m * E_DIM + bn + tx * 8;
    const float* bp = bias + bn + tx * 8;
    float4 v0, v1;
    v0.x = (acc[i][0] + bp[0]) * scale;
    v0.y = (acc[i][1] + bp[1]) * scale;
    v0.z = (acc[i][2] + bp[2]) * scale;
    v0.w = (acc[i][3] + bp[3]) * scale;
    v1.x = (acc[i][4] + bp[4]) * scale;
    v1.y = (acc[i][5] + bp[5]) * scale;
    v1.z = (acc[i][6] + bp[6]) * scale;
    v1.w = (acc[i][7] + bp[7]) * scale;
    *(float4*)(op + 0) = v0;
    *(float4*)(op + 4) = v1;
  }
#undef STORE_TILES
#undef COMPUTE_TILE
}

// ---------------------------------------------------------------------------
// CSR row_start construction from sorted row_index.
// ---------------------------------------------------------------------------
__global__ void build_row_start(const int* __restrict__ row_index,
                                int* __restrict__ row_start) {
  const int e = blockIdx.x * blockDim.x + threadIdx.x;
  if (e >= NNZ_E) return;
  const int r0 = row_index[e];
  const int r1 = (e + 1 < NNZ_E) ? row_index[e + 1] : N_NODES;
  if (e == 0)
    for (int r = 0; r <= r0; ++r) row_start[r] = 0;
  for (int r = r0 + 1; r <= r1; ++r) row_start[r] = e + 1;
}

// ---------------------------------------------------------------------------
// Phase A: one wave per edge -> all 8 head logits (coalesced 2KB q/k rows).
// ---------------------------------------------------------------------------
__global__ __launch_bounds__(256) void edge_logits(
    const float* __restrict__ q, const float* __restrict__ kfull,
    const int* __restrict__ row_index, const int* __restrict__ col_index,
    const int* __restrict__ to_col, const float* __restrict__ att_bias,
    float* __restrict__ logits) {
  const int wave = threadIdx.x >> 6;           // 0..3
  const int lane = threadIdx.x & 63;
  const int e = blockIdx.x * 4 + wave;
  const int r = row_index[e];
  const int g = to_col[col_index[e]];

  const float* qp = q + (size_t)r * E_DIM + lane * 8;
  const float* kp = kfull + (size_t)g * E_DIM + lane * 8;
  const float4 q0 = *(const float4*)(qp + 0);
  const float4 q1 = *(const float4*)(qp + 4);
  const float4 k0 = *(const float4*)(kp + 0);
  const float4 k1 = *(const float4*)(kp + 4);

  float s = q0.x * k0.x;
  s = fmaf(q0.y, k0.y, s);
  s = fmaf(q0.z, k0.z, s);
  s = fmaf(q0.w, k0.w, s);
  s = fmaf(q1.x, k1.x, s);
  s = fmaf(q1.y, k1.y, s);
  s = fmaf(q1.z, k1.z, s);
  s = fmaf(q1.w, k1.w, s);
  s += __shfl_xor(s, 1);
  s += __shfl_xor(s, 2);
  s += __shfl_xor(s, 4);
  if ((lane & 7) == 0) {
    const int h = lane >> 3;
    logits[(size_t)e * H_HEADS + h] = s + att_bias[(size_t)h * NNZ_E + e];
  }
}

// ---------------------------------------------------------------------------
// Phase B: one wave per row; lane (h,j) strided online-softmax + 3-step merge.
// ---------------------------------------------------------------------------
__global__ __launch_bounds__(64) void row_featurize(
    const float* __restrict__ logits, const int* __restrict__ row_start,
    const int* __restrict__ col_index, const float* __restrict__ dist,
    const float* __restrict__ pos, const float* __restrict__ col_pos,
    float* __restrict__ out) {
  const int r = blockIdx.x;
  const int lane = threadIdx.x;
  const int h = lane >> 3;
  const int j = lane & 7;
  const int start = row_start[r];
  const int end = row_start[r + 1];

  float m = -INFINITY, l = 0.f, accw = 0.f, a0 = 0.f, a1 = 0.f, a2 = 0.f;

  for (int e = start + j; e < end; e += 8) {
    const float s = logits[(size_t)e * H_HEADS + h];
    const float dd = dist[e];
    const float w = (dd == 0.f) ? 0.f : 1.f / dd;
    const int c = col_index[e];
    const float nm = fmaxf(m, s);
    const float sc = __expf(m - nm);
    const float p = __expf(s - nm);
    m = nm;
    l = fmaf(l, sc, p);
    const float pw = p * w;
    accw = fmaf(accw, sc, pw);
    a0 = fmaf(a0, sc, pw * col_pos[c * 3 + 0]);
    a1 = fmaf(a1, sc, pw * col_pos[c * 3 + 1]);
    a2 = fmaf(a2, sc, pw * col_pos[c * 3 + 2]);
  }

#pragma unroll
  for (int off = 1; off < 8; off <<= 1) {
    const float mo = __shfl_xor(m, off);
    const float lo = __shfl_xor(l, off);
    const float wo = __shfl_xor(accw, off);
    const float b0 = __shfl_xor(a0, off);
    const float b1 = __shfl_xor(a1, off);
    const float b2 = __shfl_xor(a2, off);
    const float nm = fmaxf(m, mo);
    const float s1 = __expf(fmaxf(m - nm, -80.f));  // NaN (inf-inf) -> -80
    const float s2 = __expf(fmaxf(mo - nm, -80.f));
    m = nm;
    l = l * s1 + lo * s2;
    accw = accw * s1 + wo * s2;
    a0 = a0 * s1 + b0 * s2;
    a1 = a1 * s1 + b1 * s2;
    a2 = a2 * s1 + b2 * s2;
  }

  if (j == 0) {
    const float invz = (l > 0.f) ? 1.f / l : 0.f;
    const float avg = accw * invz;
    const float v0 = a0 * invz - avg * pos[r * 3 + 0];
    const float v1 = a1 * invz - avg * pos[r * 3 + 1];
    const float v2 = a2 * invz - avg * pos[r * 3 + 2];
    const float nrm = sqrtf(v0 * v0 + v1 * v1 + v2 * v2);
    const float invn = 1.f / fmaxf(nrm, 1e-12f);
    float4 o;
    o.x = v0 * invn; o.y = v1 * invn; o.z = v2 * invn; o.w = avg;
    *(float4*)(out + (size_t)r * (H_HEADS * 4) + h * 4) = o;
  }
}

// ---------------------------------------------------------------------------
extern "C" void kernel_launch(void* const* d_in, const int* in_sizes, int n_in,
                              void* d_out, int out_size, void* d_ws,
                              size_t ws_size, hipStream_t stream) {
  const float* x        = (const float*)d_in[0];
  const int* row_index  = (const int*)d_in[1];
  const int* col_index  = (const int*)d_in[2];
  const int* to_col     = (const int*)d_in[3];
  const float* att_bias = (const float*)d_in[4];
  const float* dist     = (const float*)d_in[5];
  const float* pos      = (const float*)d_in[6];
  const float* col_pos  = (const float*)d_in[7];
  const float* q_w      = (const float*)d_in[8];
  const float* q_b      = (const float*)d_in[9];
  const float* k_w      = (const float*)d_in[10];
  const float* k_b      = (const float*)d_in[11];
  float* out = (float*)d_out;

  // ws: q [N*E] | kfull [N*E] | logits [NNZ*H] | row_start [N+1]
  float* q = (float*)d_ws;
  float* kfull = q + (size_t)N_NODES * E_DIM;
  float* logits = kfull + (size_t)N_NODES * E_DIM;
  int* row_start = (int*)(logits + (size_t)NNZ_E * H_HEADS);

  dim3 gg(N_NODES / 128, E_DIM / 128, 2);
  gemm_qk<<<gg, 256, 0, stream>>>(x, q_w, q_b, k_w, k_b, q, kfull);
  build_row_start<<<NNZ_E / 256, 256, 0, stream>>>(row_index, row_start);
  edge_logits<<<NNZ_E / 4, 256, 0, stream>>>(q, kfull, row_index, col_index,
                                             to_col, att_bias, logits);
  row_featurize<<<N_NODES, 64, 0, stream>>>(logits, row_start, col_index,
                                            dist, pos, col_pos, out);
}

// Round 4
// 499.246 us; speedup vs baseline: 2.0380x; 1.3935x over previous
//
#include <hip/hip_runtime.h>
#include <math.h>
#include <stdint.h>

#define N_NODES 32768
#define E_DIM   512
#define H_HEADS 8
#define D_HEAD  64
#define NNZ_E   524288

typedef __attribute__((ext_vector_type(4))) float f32x4;
typedef __attribute__((ext_vector_type(8))) short bf16x8;  // 8 bf16 = 4 VGPRs

__device__ __forceinline__ unsigned short f32_to_bf16_rne(float f) {
  union { float f; uint32_t u; } v; v.f = f;
  const uint32_t u = v.u;
  return (unsigned short)((u + 0x7FFFu + ((u >> 16) & 1u)) >> 16);
}
__device__ __forceinline__ float bf16_to_f32(unsigned short h) {
  union { uint32_t u; float f; } v; v.u = ((uint32_t)h) << 16;
  return v.f;
}

// async 16B global->LDS (wave-uniform LDS base + lane*16)
__device__ __forceinline__ void async16(const unsigned short* g, unsigned short* l) {
  __builtin_amdgcn_global_load_lds(
      (const __attribute__((address_space(1))) void*)g,
      (__attribute__((address_space(3))) void*)l, 16, 0, 0);
}

// ---------------------------------------------------------------------------
// Split fp32 matrix [rows][512] into bf16 hi|lo packed as [rows][1024]:
// dst[r][c] = bf16(src[r][c]); dst[r][512+c] = bf16(src[r][c] - hi).
// 4 elems/thread.
// ---------------------------------------------------------------------------
__global__ __launch_bounds__(256) void cvt_split(
    const float* __restrict__ src, unsigned short* __restrict__ dst) {
  const int t = blockIdx.x * 256 + threadIdx.x;
  const int r = t >> 7;            // 128 float4 per row
  const int c4 = (t & 127) << 2;
  const float4 v = *(const float4*)(src + (size_t)r * 512 + c4);
  ushort4 hi, lo;
  hi.x = f32_to_bf16_rne(v.x); lo.x = f32_to_bf16_rne(v.x - bf16_to_f32(hi.x));
  hi.y = f32_to_bf16_rne(v.y); lo.y = f32_to_bf16_rne(v.y - bf16_to_f32(hi.y));
  hi.z = f32_to_bf16_rne(v.z); lo.z = f32_to_bf16_rne(v.z - bf16_to_f32(hi.z));
  hi.w = f32_to_bf16_rne(v.w); lo.w = f32_to_bf16_rne(v.w - bf16_to_f32(hi.w));
  *(ushort4*)(dst + (size_t)r * 1024 + c4) = hi;
  *(ushort4*)(dst + (size_t)r * 1024 + 512 + c4) = lo;
}

// ---------------------------------------------------------------------------
// Split-bf16 MFMA GEMM: out[m,n] = (sum_k x[m,k]*w[n,k] + b[n]) * scale
// via 3 bf16 term-GEMMs (hi@hi + lo@hi + hi@lo), K' = 3*512.
// 128x128 block, BK=32, 4 waves, each 64x64 via 4x4 grid of 16x16x32 MFMA.
// Staging: global_load_lds width=16 (m97 pattern). blockIdx.z: 0=q, 1=k.
// ---------------------------------------------------------------------------
__global__ __launch_bounds__(256) void gemm_mfma(
    const unsigned short* __restrict__ xs,   // [N][1024] hi|lo
    const unsigned short* __restrict__ wqs,  // [512][1024] hi|lo
    const unsigned short* __restrict__ wks,
    const float* __restrict__ q_b, const float* __restrict__ k_b,
    float* __restrict__ qout, float* __restrict__ kout) {
  __shared__ unsigned short As[128 * 32];
  __shared__ unsigned short Bs[128 * 32];
  const int tid = threadIdx.x;
  const int w = tid >> 6;        // wave 0..3
  const int l = tid & 63;
  const bool is_q = (blockIdx.z == 0);
  const unsigned short* __restrict__ ws = is_q ? wqs : wks;
  const float* __restrict__ bias = is_q ? q_b : k_b;
  float* __restrict__ out = is_q ? qout : kout;
  const float scale = is_q ? 0.125f : 1.0f;

  const int bm = blockIdx.x * 128;
  const int bn = blockIdx.y * 128;
  const int wm = (w & 1) * 64;   // wave's m-quadrant
  const int wn = (w >> 1) * 64;  // wave's n-quadrant

  f32x4 acc[4][4];
#pragma unroll
  for (int i = 0; i < 4; ++i)
#pragma unroll
    for (int j = 0; j < 4; ++j) acc[i][j] = (f32x4){0.f, 0.f, 0.f, 0.f};

  // staging map: chunk c (1KB) = rows 16c..16c+15 of the [128][32] bf16 tile;
  // lane l in chunk: row = 16c + l/4, bf16-col = (l&3)*8. Wave w does chunks
  // {w, w+4} of A and of B.
  const int sr0 = w * 16 + (l >> 2);
  const int sr1 = sr0 + 64;
  const int sc = (l & 3) * 8;

  // fragment map (16x16x32): lane l -> row l&15, k-offset (l>>4)*8
  const int fr = l & 15;
  const int fc = (l >> 4) * 8;

  for (int t = 0; t < 3; ++t) {
    const int aoff = (t == 1) ? 512 : 0;   // x_lo for term 1
    const int boff = (t == 2) ? 512 : 0;   // w_lo for term 2
    for (int k0 = 0; k0 < 512; k0 += 32) {
      async16(xs + (size_t)(bm + sr0) * 1024 + aoff + k0 + sc, As + w * 512);
      async16(xs + (size_t)(bm + sr1) * 1024 + aoff + k0 + sc, As + (w + 4) * 512);
      async16(ws + (size_t)(bn + sr0) * 1024 + boff + k0 + sc, Bs + w * 512);
      async16(ws + (size_t)(bn + sr1) * 1024 + boff + k0 + sc, Bs + (w + 4) * 512);
      __syncthreads();

      bf16x8 af[4], bf[4];
#pragma unroll
      for (int i = 0; i < 4; ++i) {
        af[i] = *(const bf16x8*)(As + (wm + i * 16 + fr) * 32 + fc);
        bf[i] = *(const bf16x8*)(Bs + (wn + i * 16 + fr) * 32 + fc);
      }
#pragma unroll
      for (int i = 0; i < 4; ++i)
#pragma unroll
        for (int j = 0; j < 4; ++j)
          acc[i][j] = __builtin_amdgcn_mfma_f32_16x16x32_bf16(
              af[i], bf[j], acc[i][j], 0, 0, 0);
      __syncthreads();
    }
  }

  // epilogue: C/D layout col = l&15 (n), row = (l>>4)*4 + reg (m)
  const int cn = l & 15;
  const int cm4 = (l >> 4) * 4;
  float bvals[4];
#pragma unroll
  for (int j = 0; j < 4; ++j) bvals[j] = bias[bn + wn + j * 16 + cn];
#pragma unroll
  for (int i = 0; i < 4; ++i) {
#pragma unroll
    for (int r = 0; r < 4; ++r) {
      const int m = bm + wm + i * 16 + cm4 + r;
      float* op = out + (size_t)m * 512 + bn + wn + cn;
#pragma unroll
      for (int j = 0; j < 4; ++j)
        op[j * 16] = (acc[i][j][r] + bvals[j]) * scale;
    }
  }
}

// ---------------------------------------------------------------------------
// CSR row_start construction from sorted row_index.
// ---------------------------------------------------------------------------
__global__ void build_row_start(const int* __restrict__ row_index,
                                int* __restrict__ row_start) {
  const int e = blockIdx.x * blockDim.x + threadIdx.x;
  if (e >= NNZ_E) return;
  const int r0 = row_index[e];
  const int r1 = (e + 1 < NNZ_E) ? row_index[e + 1] : N_NODES;
  if (e == 0)
    for (int r = 0; r <= r0; ++r) row_start[r] = 0;
  for (int r = r0 + 1; r <= r1; ++r) row_start[r] = e + 1;
}

// ---------------------------------------------------------------------------
// Phase A: one wave per edge -> all 8 head logits (coalesced 2KB q/k rows).
// ---------------------------------------------------------------------------
__global__ __launch_bounds__(256) void edge_logits(
    const float* __restrict__ q, const float* __restrict__ kfull,
    const int* __restrict__ row_index, const int* __restrict__ col_index,
    const int* __restrict__ to_col, const float* __restrict__ att_bias,
    float* __restrict__ logits) {
  const int wave = threadIdx.x >> 6;
  const int lane = threadIdx.x & 63;
  const int e = blockIdx.x * 4 + wave;
  const int r = row_index[e];
  const int g = to_col[col_index[e]];

  const float* qp = q + (size_t)r * E_DIM + lane * 8;
  const float* kp = kfull + (size_t)g * E_DIM + lane * 8;
  const float4 q0 = *(const float4*)(qp + 0);
  const float4 q1 = *(const float4*)(qp + 4);
  const float4 k0 = *(const float4*)(kp + 0);
  const float4 k1 = *(const float4*)(kp + 4);

  float s = q0.x * k0.x;
  s = fmaf(q0.y, k0.y, s);
  s = fmaf(q0.z, k0.z, s);
  s = fmaf(q0.w, k0.w, s);
  s = fmaf(q1.x, k1.x, s);
  s = fmaf(q1.y, k1.y, s);
  s = fmaf(q1.z, k1.z, s);
  s = fmaf(q1.w, k1.w, s);
  s += __shfl_xor(s, 1);
  s += __shfl_xor(s, 2);
  s += __shfl_xor(s, 4);
  if ((lane & 7) == 0) {
    const int h = lane >> 3;
    logits[(size_t)e * H_HEADS + h] = s + att_bias[(size_t)h * NNZ_E + e];
  }
}

// ---------------------------------------------------------------------------
// Phase B: one wave per row; lane (h,j) strided online-softmax + 3-step merge.
// ---------------------------------------------------------------------------
__global__ __launch_bounds__(64) void row_featurize(
    const float* __restrict__ logits, const int* __restrict__ row_start,
    const int* __restrict__ col_index, const float* __restrict__ dist,
    const float* __restrict__ pos, const float* __restrict__ col_pos,
    float* __restrict__ out) {
  const int r = blockIdx.x;
  const int lane = threadIdx.x;
  const int h = lane >> 3;
  const int j = lane & 7;
  const int start = row_start[r];
  const int end = row_start[r + 1];

  float m = -INFINITY, l = 0.f, accw = 0.f, a0 = 0.f, a1 = 0.f, a2 = 0.f;

  for (int e = start + j; e < end; e += 8) {
    const float s = logits[(size_t)e * H_HEADS + h];
    const float dd = dist[e];
    const float w = (dd == 0.f) ? 0.f : 1.f / dd;
    const int c = col_index[e];
    const float nm = fmaxf(m, s);
    const float sc = __expf(m - nm);
    const float p = __expf(s - nm);
    m = nm;
    l = fmaf(l, sc, p);
    const float pw = p * w;
    accw = fmaf(accw, sc, pw);
    a0 = fmaf(a0, sc, pw * col_pos[c * 3 + 0]);
    a1 = fmaf(a1, sc, pw * col_pos[c * 3 + 1]);
    a2 = fmaf(a2, sc, pw * col_pos[c * 3 + 2]);
  }

#pragma unroll
  for (int off = 1; off < 8; off <<= 1) {
    const float mo = __shfl_xor(m, off);
    const float lo = __shfl_xor(l, off);
    const float wo = __shfl_xor(accw, off);
    const float b0 = __shfl_xor(a0, off);
    const float b1 = __shfl_xor(a1, off);
    const float b2 = __shfl_xor(a2, off);
    const float nm = fmaxf(m, mo);
    const float s1 = __expf(fmaxf(m - nm, -80.f));  // NaN (inf-inf) -> -80
    const float s2 = __expf(fmaxf(mo - nm, -80.f));
    m = nm;
    l = l * s1 + lo * s2;
    accw = accw * s1 + wo * s2;
    a0 = a0 * s1 + b0 * s2;
    a1 = a1 * s1 + b1 * s2;
    a2 = a2 * s1 + b2 * s2;
  }

  if (j == 0) {
    const float invz = (l > 0.f) ? 1.f / l : 0.f;
    const float avg = accw * invz;
    const float v0 = a0 * invz - avg * pos[r * 3 + 0];
    const float v1 = a1 * invz - avg * pos[r * 3 + 1];
    const float v2 = a2 * invz - avg * pos[r * 3 + 2];
    const float nrm = sqrtf(v0 * v0 + v1 * v1 + v2 * v2);
    const float invn = 1.f / fmaxf(nrm, 1e-12f);
    float4 o;
    o.x = v0 * invn; o.y = v1 * invn; o.z = v2 * invn; o.w = avg;
    *(float4*)(out + (size_t)r * (H_HEADS * 4) + h * 4) = o;
  }
}

// ---------------------------------------------------------------------------
extern "C" void kernel_launch(void* const* d_in, const int* in_sizes, int n_in,
                              void* d_out, int out_size, void* d_ws,
                              size_t ws_size, hipStream_t stream) {
  const float* x        = (const float*)d_in[0];
  const int* row_index  = (const int*)d_in[1];
  const int* col_index  = (const int*)d_in[2];
  const int* to_col     = (const int*)d_in[3];
  const float* att_bias = (const float*)d_in[4];
  const float* dist     = (const float*)d_in[5];
  const float* pos      = (const float*)d_in[6];
  const float* col_pos  = (const float*)d_in[7];
  const float* q_w      = (const float*)d_in[8];
  const float* q_b      = (const float*)d_in[9];
  const float* k_w      = (const float*)d_in[10];
  const float* k_b      = (const float*)d_in[11];
  float* out = (float*)d_out;

  // ws: q[N*E f32] | kfull[N*E f32] | xsplit[N*1024 bf16] (aliased by logits)
  //     | wq_s[512*1024 bf16] | wk_s[...] | row_start[N+1]
  // xsplit is dead after gemm_mfma; logits is born in edge_logits -> alias OK.
  float* q = (float*)d_ws;
  float* kfull = q + (size_t)N_NODES * E_DIM;
  unsigned short* xsplit = (unsigned short*)(kfull + (size_t)N_NODES * E_DIM);
  float* logits = (float*)xsplit;  // 16 MB inside xsplit's 64 MB
  unsigned short* wq_s = xsplit + (size_t)N_NODES * 1024;
  unsigned short* wk_s = wq_s + 512 * 1024;
  int* row_start = (int*)(wk_s + 512 * 1024);

  cvt_split<<<N_NODES / 2, 256, 0, stream>>>(x, xsplit);
  cvt_split<<<256, 256, 0, stream>>>(q_w, wq_s);
  cvt_split<<<256, 256, 0, stream>>>(k_w, wk_s);

  dim3 gg(N_NODES / 128, E_DIM / 128, 2);
  gemm_mfma<<<gg, 256, 0, stream>>>(xsplit, wq_s, wk_s, q_b, k_b, q, kfull);

  build_row_start<<<NNZ_E / 256, 256, 0, stream>>>(row_index, row_start);
  edge_logits<<<NNZ_E / 4, 256, 0, stream>>>(q, kfull, row_index, col_index,
                                             to_col, att_bias, logits);
  row_featurize<<<N_NODES, 64, 0, stream>>>(logits, row_start, col_index,
                                            dist, pos, col_pos, out);
}

// Round 5
// 459.172 us; speedup vs baseline: 2.2159x; 1.0873x over previous
//
#include <hip/hip_runtime.h>
#include <math.h>
#include <stdint.h>

#define N_NODES 32768
#define E_DIM   512
#define H_HEADS 8
#define D_HEAD  64
#define NNZ_E   524288

typedef __attribute__((ext_vector_type(4))) float f32x4;
typedef __attribute__((ext_vector_type(8))) short bf16x8;  // 8 bf16 = 4 VGPRs

__device__ __forceinline__ unsigned short f32_to_bf16_rne(float f) {
  union { float f; uint32_t u; } v; v.f = f;
  const uint32_t u = v.u;
  return (unsigned short)((u + 0x7FFFu + ((u >> 16) & 1u)) >> 16);
}
__device__ __forceinline__ float bf16_to_f32(unsigned short h) {
  union { uint32_t u; float f; } v; v.u = ((uint32_t)h) << 16;
  return v.f;
}

// async 16B global->LDS (wave-uniform LDS base + lane*16)
__device__ __forceinline__ void async16(const unsigned short* g, unsigned short* l) {
  __builtin_amdgcn_global_load_lds(
      (const __attribute__((address_space(1))) void*)g,
      (__attribute__((address_space(3))) void*)l, 16, 0, 0);
}

// ---------------------------------------------------------------------------
// Split fp32 matrix [rows][512] into bf16 hi|lo packed as [rows][1024].
// ---------------------------------------------------------------------------
__global__ __launch_bounds__(256) void cvt_split(
    const float* __restrict__ src, unsigned short* __restrict__ dst) {
  const int t = blockIdx.x * 256 + threadIdx.x;
  const int r = t >> 7;            // 128 float4 per row
  const int c4 = (t & 127) << 2;
  const float4 v = *(const float4*)(src + (size_t)r * 512 + c4);
  ushort4 hi, lo;
  hi.x = f32_to_bf16_rne(v.x); lo.x = f32_to_bf16_rne(v.x - bf16_to_f32(hi.x));
  hi.y = f32_to_bf16_rne(v.y); lo.y = f32_to_bf16_rne(v.y - bf16_to_f32(hi.y));
  hi.z = f32_to_bf16_rne(v.z); lo.z = f32_to_bf16_rne(v.z - bf16_to_f32(hi.z));
  hi.w = f32_to_bf16_rne(v.w); lo.w = f32_to_bf16_rne(v.w - bf16_to_f32(hi.w));
  *(ushort4*)(dst + (size_t)r * 1024 + c4) = hi;
  *(ushort4*)(dst + (size_t)r * 1024 + 512 + c4) = lo;
}

// ---------------------------------------------------------------------------
// Split-bf16 MFMA GEMM (3-term hi/lo), 128x128 block, BK=32, 4 waves,
// 4x4 grid of 16x16x32 bf16 MFMA per wave. blockIdx.z: 0=q, 1=k.
// ---------------------------------------------------------------------------
__global__ __launch_bounds__(256) void gemm_mfma(
    const unsigned short* __restrict__ xs,   // [N][1024] hi|lo
    const unsigned short* __restrict__ wqs,  // [512][1024] hi|lo
    const unsigned short* __restrict__ wks,
    const float* __restrict__ q_b, const float* __restrict__ k_b,
    float* __restrict__ qout, float* __restrict__ kout) {
  __shared__ unsigned short As[128 * 32];
  __shared__ unsigned short Bs[128 * 32];
  const int tid = threadIdx.x;
  const int w = tid >> 6;        // wave 0..3
  const int l = tid & 63;
  const bool is_q = (blockIdx.z == 0);
  const unsigned short* __restrict__ ws = is_q ? wqs : wks;
  const float* __restrict__ bias = is_q ? q_b : k_b;
  float* __restrict__ out = is_q ? qout : kout;
  const float scale = is_q ? 0.125f : 1.0f;

  const int bm = blockIdx.x * 128;
  const int bn = blockIdx.y * 128;
  const int wm = (w & 1) * 64;   // wave's m-quadrant
  const int wn = (w >> 1) * 64;  // wave's n-quadrant

  f32x4 acc[4][4];
#pragma unroll
  for (int i = 0; i < 4; ++i)
#pragma unroll
    for (int j = 0; j < 4; ++j) acc[i][j] = (f32x4){0.f, 0.f, 0.f, 0.f};

  const int sr0 = w * 16 + (l >> 2);
  const int sr1 = sr0 + 64;
  const int sc = (l & 3) * 8;
  const int fr = l & 15;
  const int fc = (l >> 4) * 8;

  for (int t = 0; t < 3; ++t) {
    const int aoff = (t == 1) ? 512 : 0;   // x_lo for term 1
    const int boff = (t == 2) ? 512 : 0;   // w_lo for term 2
    for (int k0 = 0; k0 < 512; k0 += 32) {
      async16(xs + (size_t)(bm + sr0) * 1024 + aoff + k0 + sc, As + w * 512);
      async16(xs + (size_t)(bm + sr1) * 1024 + aoff + k0 + sc, As + (w + 4) * 512);
      async16(ws + (size_t)(bn + sr0) * 1024 + boff + k0 + sc, Bs + w * 512);
      async16(ws + (size_t)(bn + sr1) * 1024 + boff + k0 + sc, Bs + (w + 4) * 512);
      __syncthreads();

      bf16x8 af[4], bf[4];
#pragma unroll
      for (int i = 0; i < 4; ++i) {
        af[i] = *(const bf16x8*)(As + (wm + i * 16 + fr) * 32 + fc);
        bf[i] = *(const bf16x8*)(Bs + (wn + i * 16 + fr) * 32 + fc);
      }
#pragma unroll
      for (int i = 0; i < 4; ++i)
#pragma unroll
        for (int j = 0; j < 4; ++j)
          acc[i][j] = __builtin_amdgcn_mfma_f32_16x16x32_bf16(
              af[i], bf[j], acc[i][j], 0, 0, 0);
      __syncthreads();
    }
  }

  const int cn = l & 15;
  const int cm4 = (l >> 4) * 4;
  float bvals[4];
#pragma unroll
  for (int j = 0; j < 4; ++j) bvals[j] = bias[bn + wn + j * 16 + cn];
#pragma unroll
  for (int i = 0; i < 4; ++i) {
#pragma unroll
    for (int r = 0; r < 4; ++r) {
      const int m = bm + wm + i * 16 + cm4 + r;
      float* op = out + (size_t)m * 512 + bn + wn + cn;
#pragma unroll
      for (int j = 0; j < 4; ++j)
        op[j * 16] = (acc[i][j][r] + bvals[j]) * scale;
    }
  }
}

// ---------------------------------------------------------------------------
// Fused aux: ge[e] = to_col[col_index[e]]  +  CSR row_start from sorted rows.
// ---------------------------------------------------------------------------
__global__ void build_aux(const int* __restrict__ row_index,
                          const int* __restrict__ col_index,
                          const int* __restrict__ to_col,
                          int* __restrict__ row_start,
                          int* __restrict__ ge) {
  const int e = blockIdx.x * blockDim.x + threadIdx.x;
  if (e >= NNZ_E) return;
  ge[e] = to_col[col_index[e]];
  const int r0 = row_index[e];
  const int r1 = (e + 1 < NNZ_E) ? row_index[e + 1] : N_NODES;
  if (e == 0)
    for (int r = 0; r <= r0; ++r) row_start[r] = 0;
  for (int r = r0 + 1; r <= r1; ++r) row_start[r] = e + 1;
}

// ---------------------------------------------------------------------------
// Phase A: 4 edges per wave, batched. Scalarized index loads (s_load via
// readfirstlane) then all 16 dwordx4 q/k loads issued back-to-back (8 KB
// in flight per wave) before any compute -> 4x the memory-level parallelism
// of the 1-edge-per-wave version (which measured 23% VALUBusy, latency-bound).
// ---------------------------------------------------------------------------
__global__ __launch_bounds__(256) void edge_logits(
    const float* __restrict__ q, const float* __restrict__ kfull,
    const int* __restrict__ row_index, const int* __restrict__ ge,
    const float* __restrict__ att_bias, float* __restrict__ logits) {
  const int wave = threadIdx.x >> 6;
  const int lane = threadIdx.x & 63;
  // wave-uniform base edge; readfirstlane makes it provably scalar -> s_load
  const int e0 = __builtin_amdgcn_readfirstlane((blockIdx.x * 4 + wave) * 4);

  int r[4], g[4];
#pragma unroll
  for (int i = 0; i < 4; ++i) {
    r[i] = row_index[e0 + i];
    g[i] = ge[e0 + i];
  }

  const int lo = lane * 8;
  float4 qv[4][2], kv[4][2];
#pragma unroll
  for (int i = 0; i < 4; ++i) {
    const float* kp = kfull + (size_t)g[i] * E_DIM + lo;
    kv[i][0] = *(const float4*)(kp + 0);
    kv[i][1] = *(const float4*)(kp + 4);
  }
#pragma unroll
  for (int i = 0; i < 4; ++i) {
    const float* qp = q + (size_t)r[i] * E_DIM + lo;
    qv[i][0] = *(const float4*)(qp + 0);
    qv[i][1] = *(const float4*)(qp + 4);
  }

  const int h = lane >> 3;
#pragma unroll
  for (int i = 0; i < 4; ++i) {
    float s = qv[i][0].x * kv[i][0].x;
    s = fmaf(qv[i][0].y, kv[i][0].y, s);
    s = fmaf(qv[i][0].z, kv[i][0].z, s);
    s = fmaf(qv[i][0].w, kv[i][0].w, s);
    s = fmaf(qv[i][1].x, kv[i][1].x, s);
    s = fmaf(qv[i][1].y, kv[i][1].y, s);
    s = fmaf(qv[i][1].z, kv[i][1].z, s);
    s = fmaf(qv[i][1].w, kv[i][1].w, s);
    s += __shfl_xor(s, 1);
    s += __shfl_xor(s, 2);
    s += __shfl_xor(s, 4);
    if ((lane & 7) == 0) {
      logits[(size_t)(e0 + i) * H_HEADS + h] =
          s + att_bias[(size_t)h * NNZ_E + e0 + i];
    }
  }
}

// ---------------------------------------------------------------------------
// Phase B: one wave per row; lane (h,j) strided online-softmax + 3-step merge.
// ---------------------------------------------------------------------------
__global__ __launch_bounds__(64) void row_featurize(
    const float* __restrict__ logits, const int* __restrict__ row_start,
    const int* __restrict__ col_index, const float* __restrict__ dist,
    const float* __restrict__ pos, const float* __restrict__ col_pos,
    float* __restrict__ out) {
  const int r = blockIdx.x;
  const int lane = threadIdx.x;
  const int h = lane >> 3;
  const int j = lane & 7;
  const int start = row_start[r];
  const int end = row_start[r + 1];

  float m = -INFINITY, l = 0.f, accw = 0.f, a0 = 0.f, a1 = 0.f, a2 = 0.f;

  for (int e = start + j; e < end; e += 8) {
    const float s = logits[(size_t)e * H_HEADS + h];
    const float dd = dist[e];
    const float w = (dd == 0.f) ? 0.f : 1.f / dd;
    const int c = col_index[e];
    const float nm = fmaxf(m, s);
    const float sc = __expf(m - nm);
    const float p = __expf(s - nm);
    m = nm;
    l = fmaf(l, sc, p);
    const float pw = p * w;
    accw = fmaf(accw, sc, pw);
    a0 = fmaf(a0, sc, pw * col_pos[c * 3 + 0]);
    a1 = fmaf(a1, sc, pw * col_pos[c * 3 + 1]);
    a2 = fmaf(a2, sc, pw * col_pos[c * 3 + 2]);
  }

#pragma unroll
  for (int off = 1; off < 8; off <<= 1) {
    const float mo = __shfl_xor(m, off);
    const float lo = __shfl_xor(l, off);
    const float wo = __shfl_xor(accw, off);
    const float b0 = __shfl_xor(a0, off);
    const float b1 = __shfl_xor(a1, off);
    const float b2 = __shfl_xor(a2, off);
    const float nm = fmaxf(m, mo);
    const float s1 = __expf(fmaxf(m - nm, -80.f));  // NaN (inf-inf) -> -80
    const float s2 = __expf(fmaxf(mo - nm, -80.f));
    m = nm;
    l = l * s1 + lo * s2;
    accw = accw * s1 + wo * s2;
    a0 = a0 * s1 + b0 * s2;
    a1 = a1 * s1 + b1 * s2;
    a2 = a2 * s1 + b2 * s2;
  }

  if (j == 0) {
    const float invz = (l > 0.f) ? 1.f / l : 0.f;
    const float avg = accw * invz;
    const float v0 = a0 * invz - avg * pos[r * 3 + 0];
    const float v1 = a1 * invz - avg * pos[r * 3 + 1];
    const float v2 = a2 * invz - avg * pos[r * 3 + 2];
    const float nrm = sqrtf(v0 * v0 + v1 * v1 + v2 * v2);
    const float invn = 1.f / fmaxf(nrm, 1e-12f);
    float4 o;
    o.x = v0 * invn; o.y = v1 * invn; o.z = v2 * invn; o.w = avg;
    *(float4*)(out + (size_t)r * (H_HEADS * 4) + h * 4) = o;
  }
}

// ---------------------------------------------------------------------------
extern "C" void kernel_launch(void* const* d_in, const int* in_sizes, int n_in,
                              void* d_out, int out_size, void* d_ws,
                              size_t ws_size, hipStream_t stream) {
  const float* x        = (const float*)d_in[0];
  const int* row_index  = (const int*)d_in[1];
  const int* col_index  = (const int*)d_in[2];
  const int* to_col     = (const int*)d_in[3];
  const float* att_bias = (const float*)d_in[4];
  const float* dist     = (const float*)d_in[5];
  const float* pos      = (const float*)d_in[6];
  const float* col_pos  = (const float*)d_in[7];
  const float* q_w      = (const float*)d_in[8];
  const float* q_b      = (const float*)d_in[9];
  const float* k_w      = (const float*)d_in[10];
  const float* k_b      = (const float*)d_in[11];
  float* out = (float*)d_out;

  // ws: q[N*E f32] | kfull[N*E f32] | xsplit[N*1024 bf16] (aliased by logits)
  //     | wq_s | wk_s | row_start[N+1] | ge[NNZ]
  float* q = (float*)d_ws;
  float* kfull = q + (size_t)N_NODES * E_DIM;
  unsigned short* xsplit = (unsigned short*)(kfull + (size_t)N_NODES * E_DIM);
  float* logits = (float*)xsplit;  // 16 MB inside xsplit's 64 MB (dead then)
  unsigned short* wq_s = xsplit + (size_t)N_NODES * 1024;
  unsigned short* wk_s = wq_s + 512 * 1024;
  int* row_start = (int*)(wk_s + 512 * 1024);
  int* ge = row_start + (N_NODES + 1);

  cvt_split<<<N_NODES / 2, 256, 0, stream>>>(x, xsplit);
  cvt_split<<<256, 256, 0, stream>>>(q_w, wq_s);
  cvt_split<<<256, 256, 0, stream>>>(k_w, wk_s);

  dim3 gg(N_NODES / 128, E_DIM / 128, 2);
  gemm_mfma<<<gg, 256, 0, stream>>>(xsplit, wq_s, wk_s, q_b, k_b, q, kfull);

  build_aux<<<NNZ_E / 256, 256, 0, stream>>>(row_index, col_index, to_col,
                                             row_start, ge);
  edge_logits<<<NNZ_E / 16, 256, 0, stream>>>(q, kfull, row_index, ge,
                                              att_bias, logits);
  row_featurize<<<N_NODES, 64, 0, stream>>>(logits, row_start, col_index,
                                            dist, pos, col_pos, out);
}

// Round 6
// 391.864 us; speedup vs baseline: 2.5965x; 1.1718x over previous
//
#include <hip/hip_runtime.h>
#include <math.h>
#include <stdint.h>

#define N_NODES 32768
#define E_DIM   512
#define H_HEADS 8
#define D_HEAD  64
#define NNZ_E   524288

typedef __attribute__((ext_vector_type(4))) float f32x4;
typedef __attribute__((ext_vector_type(8))) short bf16x8;  // 8 bf16 = 4 VGPRs
typedef __attribute__((ext_vector_type(8))) short s16x8;

__device__ __forceinline__ unsigned short f32_to_bf16_rne(float f) {
  union { float f; uint32_t u; } v; v.f = f;
  const uint32_t u = v.u;
  return (unsigned short)((u + 0x7FFFu + ((u >> 16) & 1u)) >> 16);
}
__device__ __forceinline__ float bf16_to_f32(unsigned short h) {
  union { uint32_t u; float f; } v; v.u = ((uint32_t)h) << 16;
  return v.f;
}

// async 16B global->LDS (wave-uniform LDS base + lane*16)
__device__ __forceinline__ void async16(const unsigned short* g, unsigned short* l) {
  __builtin_amdgcn_global_load_lds(
      (const __attribute__((address_space(1))) void*)g,
      (__attribute__((address_space(3))) void*)l, 16, 0, 0);
}

// ---------------------------------------------------------------------------
// Split fp32 matrix [rows][512] into bf16 hi|lo packed as [rows][1024].
// ---------------------------------------------------------------------------
__global__ __launch_bounds__(256) void cvt_split(
    const float* __restrict__ src, unsigned short* __restrict__ dst) {
  const int t = blockIdx.x * 256 + threadIdx.x;
  const int r = t >> 7;            // 128 float4 per row
  const int c4 = (t & 127) << 2;
  const float4 v = *(const float4*)(src + (size_t)r * 512 + c4);
  ushort4 hi, lo;
  hi.x = f32_to_bf16_rne(v.x); lo.x = f32_to_bf16_rne(v.x - bf16_to_f32(hi.x));
  hi.y = f32_to_bf16_rne(v.y); lo.y = f32_to_bf16_rne(v.y - bf16_to_f32(hi.y));
  hi.z = f32_to_bf16_rne(v.z); lo.z = f32_to_bf16_rne(v.z - bf16_to_f32(hi.z));
  hi.w = f32_to_bf16_rne(v.w); lo.w = f32_to_bf16_rne(v.w - bf16_to_f32(hi.w));
  *(ushort4*)(dst + (size_t)r * 1024 + c4) = hi;
  *(ushort4*)(dst + (size_t)r * 1024 + 512 + c4) = lo;
}

// ---------------------------------------------------------------------------
// Split-bf16 MFMA GEMM (3-term hi/lo), 128x128 block, BK=32, 4 waves,
// 4x4 grid of 16x16x32 bf16 MFMA per wave. blockIdx.z: 0 -> q (fp32, *1/8),
// 1 -> k (int16, *4096).
// LDS XOR swizzle: 16B-chunk j of row r stored at chunk j ^ ((r>>1)&3); the
// staging side swizzles which GLOBAL chunk each lane fetches (LDS dest of
// global_load_lds is fixed at lane*16). Makes every 8-lane b128 read phase
// cover all 32 banks -> conflict-free.
// ---------------------------------------------------------------------------
__global__ __launch_bounds__(256) void gemm_mfma(
    const unsigned short* __restrict__ xs,   // [N][1024] hi|lo
    const unsigned short* __restrict__ wqs,  // [512][1024] hi|lo
    const unsigned short* __restrict__ wks,
    const float* __restrict__ q_b, const float* __restrict__ k_b,
    float* __restrict__ qout, short* __restrict__ k16) {
  __shared__ unsigned short As[128 * 32];
  __shared__ unsigned short Bs[128 * 32];
  const int tid = threadIdx.x;
  const int w = tid >> 6;        // wave 0..3
  const int l = tid & 63;
  const bool is_q = (blockIdx.z == 0);
  const unsigned short* __restrict__ ws = is_q ? wqs : wks;
  const float* __restrict__ bias = is_q ? q_b : k_b;

  const int bm = blockIdx.x * 128;
  const int bn = blockIdx.y * 128;
  const int wm = (w & 1) * 64;   // wave's m-quadrant
  const int wn = (w >> 1) * 64;  // wave's n-quadrant

  f32x4 acc[4][4];
#pragma unroll
  for (int i = 0; i < 4; ++i)
#pragma unroll
    for (int j = 0; j < 4; ++j) acc[i][j] = (f32x4){0.f, 0.f, 0.f, 0.f};

  // staging: lane l sits at LDS (row_local = l>>2, chunk = l&3); fetch the
  // global chunk (l&3) ^ swz(row_local), swz(r) = (r>>1)&3 = (l>>3)&3.
  const int sr0 = w * 16 + (l >> 2);
  const int sr1 = sr0 + 64;
  const int sc = (((l & 3) ^ ((l >> 3) & 3)) << 3);
  // fragment read: row fr = l&15, want global chunk l>>4 -> LDS chunk
  // (l>>4) ^ ((fr>>1)&3)
  const int fr = l & 15;
  const int fcs = ((((l >> 4) ^ ((fr >> 1) & 3)) & 3) << 3);

  for (int t = 0; t < 3; ++t) {
    const int aoff = (t == 1) ? 512 : 0;   // x_lo for term 1
    const int boff = (t == 2) ? 512 : 0;   // w_lo for term 2
    for (int k0 = 0; k0 < 512; k0 += 32) {
      async16(xs + (size_t)(bm + sr0) * 1024 + aoff + k0 + sc, As + w * 512);
      async16(xs + (size_t)(bm + sr1) * 1024 + aoff + k0 + sc, As + (w + 4) * 512);
      async16(ws + (size_t)(bn + sr0) * 1024 + boff + k0 + sc, Bs + w * 512);
      async16(ws + (size_t)(bn + sr1) * 1024 + boff + k0 + sc, Bs + (w + 4) * 512);
      __syncthreads();

      bf16x8 af[4], bf[4];
#pragma unroll
      for (int i = 0; i < 4; ++i) {
        af[i] = *(const bf16x8*)(As + (wm + i * 16 + fr) * 32 + fcs);
        bf[i] = *(const bf16x8*)(Bs + (wn + i * 16 + fr) * 32 + fcs);
      }
#pragma unroll
      for (int i = 0; i < 4; ++i)
#pragma unroll
        for (int j = 0; j < 4; ++j)
          acc[i][j] = __builtin_amdgcn_mfma_f32_16x16x32_bf16(
              af[i], bf[j], acc[i][j], 0, 0, 0);
      __syncthreads();
    }
  }

  // epilogue: C/D layout col = l&15 (n), row = (l>>4)*4 + reg (m)
  const int cn = l & 15;
  const int cm4 = (l >> 4) * 4;
  float bvals[4];
#pragma unroll
  for (int j = 0; j < 4; ++j) bvals[j] = bias[bn + wn + j * 16 + cn];
#pragma unroll
  for (int i = 0; i < 4; ++i) {
#pragma unroll
    for (int r = 0; r < 4; ++r) {
      const int m = bm + wm + i * 16 + cm4 + r;
      if (is_q) {
        float* op = qout + (size_t)m * 512 + bn + wn + cn;
#pragma unroll
        for (int j = 0; j < 4; ++j)
          op[j * 16] = (acc[i][j][r] + bvals[j]) * 0.125f;
      } else {
        short* op = k16 + (size_t)m * 512 + bn + wn + cn;
#pragma unroll
        for (int j = 0; j < 4; ++j) {
          float v = (acc[i][j][r] + bvals[j]) * 4096.f;
          v = fmaxf(fminf(v, 32767.f), -32767.f);
          op[j * 16] = (short)__float2int_rn(v);
        }
      }
    }
  }
}

// ---------------------------------------------------------------------------
// Fused aux: ge[e] = to_col[col_index[e]]  +  CSR row_start from sorted rows.
// ---------------------------------------------------------------------------
__global__ void build_aux(const int* __restrict__ row_index,
                          const int* __restrict__ col_index,
                          const int* __restrict__ to_col,
                          int* __restrict__ row_start,
                          int* __restrict__ ge) {
  const int e = blockIdx.x * blockDim.x + threadIdx.x;
  if (e >= NNZ_E) return;
  ge[e] = to_col[col_index[e]];
  const int r0 = row_index[e];
  const int r1 = (e + 1 < NNZ_E) ? row_index[e + 1] : N_NODES;
  if (e == 0)
    for (int r = 0; r <= r0; ++r) row_start[r] = 0;
  for (int r = r0 + 1; r <= r1; ++r) row_start[r] = e + 1;
}

// ---------------------------------------------------------------------------
// Phase A: 4 edges per wave, batched loads. k gathered as int16 (16B/lane/edge
// vs 32B fp32) -> gather traffic halved. logit = (q . k_int)*2^-12 + bias.
// ---------------------------------------------------------------------------
__global__ __launch_bounds__(256) void edge_logits(
    const float* __restrict__ q, const short* __restrict__ k16,
    const int* __restrict__ row_index, const int* __restrict__ ge,
    const float* __restrict__ att_bias, float* __restrict__ logits) {
  const int wave = threadIdx.x >> 6;
  const int lane = threadIdx.x & 63;
  const int e0 = __builtin_amdgcn_readfirstlane((blockIdx.x * 4 + wave) * 4);

  int r[4], g[4];
#pragma unroll
  for (int i = 0; i < 4; ++i) {
    r[i] = row_index[e0 + i];
    g[i] = ge[e0 + i];
  }

  const int lo = lane * 8;
  s16x8 kv[4];
  float4 qv[4][2];
#pragma unroll
  for (int i = 0; i < 4; ++i)
    kv[i] = *(const s16x8*)(k16 + (size_t)g[i] * E_DIM + lo);
#pragma unroll
  for (int i = 0; i < 4; ++i) {
    const float* qp = q + (size_t)r[i] * E_DIM + lo;
    qv[i][0] = *(const float4*)(qp + 0);
    qv[i][1] = *(const float4*)(qp + 4);
  }

  const int h = lane >> 3;
#pragma unroll
  for (int i = 0; i < 4; ++i) {
    float s = qv[i][0].x * (float)kv[i][0];
    s = fmaf(qv[i][0].y, (float)kv[i][1], s);
    s = fmaf(qv[i][0].z, (float)kv[i][2], s);
    s = fmaf(qv[i][0].w, (float)kv[i][3], s);
    s = fmaf(qv[i][1].x, (float)kv[i][4], s);
    s = fmaf(qv[i][1].y, (float)kv[i][5], s);
    s = fmaf(qv[i][1].z, (float)kv[i][6], s);
    s = fmaf(qv[i][1].w, (float)kv[i][7], s);
    s += __shfl_xor(s, 1);
    s += __shfl_xor(s, 2);
    s += __shfl_xor(s, 4);
    if ((lane & 7) == 0) {
      logits[(size_t)(e0 + i) * H_HEADS + h] =
          s * (1.f / 4096.f) + att_bias[(size_t)h * NNZ_E + e0 + i];
    }
  }
}

// ---------------------------------------------------------------------------
// Phase B: one wave per row; lane (h,j) strided online-softmax + 3-step merge.
// ---------------------------------------------------------------------------
__global__ __launch_bounds__(64) void row_featurize(
    const float* __restrict__ logits, const int* __restrict__ row_start,
    const int* __restrict__ col_index, const float* __restrict__ dist,
    const float* __restrict__ pos, const float* __restrict__ col_pos,
    float* __restrict__ out) {
  const int r = blockIdx.x;
  const int lane = threadIdx.x;
  const int h = lane >> 3;
  const int j = lane & 7;
  const int start = row_start[r];
  const int end = row_start[r + 1];

  float m = -INFINITY, l = 0.f, accw = 0.f, a0 = 0.f, a1 = 0.f, a2 = 0.f;

  for (int e = start + j; e < end; e += 8) {
    const float s = logits[(size_t)e * H_HEADS + h];
    const float dd = dist[e];
    const float w = (dd == 0.f) ? 0.f : 1.f / dd;
    const int c = col_index[e];
    const float nm = fmaxf(m, s);
    const float sc = __expf(m - nm);
    const float p = __expf(s - nm);
    m = nm;
    l = fmaf(l, sc, p);
    const float pw = p * w;
    accw = fmaf(accw, sc, pw);
    a0 = fmaf(a0, sc, pw * col_pos[c * 3 + 0]);
    a1 = fmaf(a1, sc, pw * col_pos[c * 3 + 1]);
    a2 = fmaf(a2, sc, pw * col_pos[c * 3 + 2]);
  }

#pragma unroll
  for (int off = 1; off < 8; off <<= 1) {
    const float mo = __shfl_xor(m, off);
    const float lo = __shfl_xor(l, off);
    const float wo = __shfl_xor(accw, off);
    const float b0 = __shfl_xor(a0, off);
    const float b1 = __shfl_xor(a1, off);
    const float b2 = __shfl_xor(a2, off);
    const float nm = fmaxf(m, mo);
    const float s1 = __expf(fmaxf(m - nm, -80.f));  // NaN (inf-inf) -> -80
    const float s2 = __expf(fmaxf(mo - nm, -80.f));
    m = nm;
    l = l * s1 + lo * s2;
    accw = accw * s1 + wo * s2;
    a0 = a0 * s1 + b0 * s2;
    a1 = a1 * s1 + b1 * s2;
    a2 = a2 * s1 + b2 * s2;
  }

  if (j == 0) {
    const float invz = (l > 0.f) ? 1.f / l : 0.f;
    const float avg = accw * invz;
    const float v0 = a0 * invz - avg * pos[r * 3 + 0];
    const float v1 = a1 * invz - avg * pos[r * 3 + 1];
    const float v2 = a2 * invz - avg * pos[r * 3 + 2];
    const float nrm = sqrtf(v0 * v0 + v1 * v1 + v2 * v2);
    const float invn = 1.f / fmaxf(nrm, 1e-12f);
    float4 o;
    o.x = v0 * invn; o.y = v1 * invn; o.z = v2 * invn; o.w = avg;
    *(float4*)(out + (size_t)r * (H_HEADS * 4) + h * 4) = o;
  }
}

// ---------------------------------------------------------------------------
extern "C" void kernel_launch(void* const* d_in, const int* in_sizes, int n_in,
                              void* d_out, int out_size, void* d_ws,
                              size_t ws_size, hipStream_t stream) {
  const float* x        = (const float*)d_in[0];
  const int* row_index  = (const int*)d_in[1];
  const int* col_index  = (const int*)d_in[2];
  const int* to_col     = (const int*)d_in[3];
  const float* att_bias = (const float*)d_in[4];
  const float* dist     = (const float*)d_in[5];
  const float* pos      = (const float*)d_in[6];
  const float* col_pos  = (const float*)d_in[7];
  const float* q_w      = (const float*)d_in[8];
  const float* q_b      = (const float*)d_in[9];
  const float* k_w      = (const float*)d_in[10];
  const float* k_b      = (const float*)d_in[11];
  float* out = (float*)d_out;

  // ws: q[N*E f32] | k16[N*E s16] | xsplit[N*1024 bf16] (aliased by logits)
  //     | wq_s | wk_s | row_start[N+1] | ge[NNZ]
  float* q = (float*)d_ws;
  short* k16 = (short*)(q + (size_t)N_NODES * E_DIM);
  unsigned short* xsplit = (unsigned short*)(k16 + (size_t)N_NODES * E_DIM);
  float* logits = (float*)xsplit;  // xsplit dead after gemm_mfma
  unsigned short* wq_s = xsplit + (size_t)N_NODES * 1024;
  unsigned short* wk_s = wq_s + 512 * 1024;
  int* row_start = (int*)(wk_s + 512 * 1024);
  int* ge = row_start + (N_NODES + 1);

  cvt_split<<<N_NODES / 2, 256, 0, stream>>>(x, xsplit);
  cvt_split<<<256, 256, 0, stream>>>(q_w, wq_s);
  cvt_split<<<256, 256, 0, stream>>>(k_w, wk_s);

  dim3 gg(N_NODES / 128, E_DIM / 128, 2);
  gemm_mfma<<<gg, 256, 0, stream>>>(xsplit, wq_s, wk_s, q_b, k_b, q, k16);

  build_aux<<<NNZ_E / 256, 256, 0, stream>>>(row_index, col_index, to_col,
                                             row_start, ge);
  edge_logits<<<NNZ_E / 16, 256, 0, stream>>>(q, k16, row_index, ge,
                                              att_bias, logits);
  row_featurize<<<N_NODES, 64, 0, stream>>>(logits, row_start, col_index,
                                            dist, pos, col_pos, out);
}

// Round 7
// 363.303 us; speedup vs baseline: 2.8006x; 1.0786x over previous
//
#include <hip/hip_runtime.h>
#include <math.h>
#include <stdint.h>

#define N_NODES 32768
#define E_DIM   512
#define H_HEADS 8
#define D_HEAD  64
#define NNZ_E   524288

typedef __attribute__((ext_vector_type(4))) float f32x4;
typedef __attribute__((ext_vector_type(8))) short bf16x8;  // 8 bf16 = 4 VGPRs
typedef __attribute__((ext_vector_type(8))) short s16x8;

__device__ __forceinline__ unsigned short f32_to_bf16_rne(float f) {
  union { float f; uint32_t u; } v; v.f = f;
  const uint32_t u = v.u;
  return (unsigned short)((u + 0x7FFFu + ((u >> 16) & 1u)) >> 16);
}
__device__ __forceinline__ float bf16_to_f32(unsigned short h) {
  union { uint32_t u; float f; } v; v.u = ((uint32_t)h) << 16;
  return v.f;
}

// async 16B global->LDS (wave-uniform LDS base + lane*16)
__device__ __forceinline__ void async16(const unsigned short* g, unsigned short* l) {
  __builtin_amdgcn_global_load_lds(
      (const __attribute__((address_space(1))) void*)g,
      (__attribute__((address_space(3))) void*)l, 16, 0, 0);
}

// ---------------------------------------------------------------------------
// Split fp32 matrix [rows][512] into bf16 hi|lo packed as [rows][1024].
// ---------------------------------------------------------------------------
__global__ __launch_bounds__(256) void cvt_split(
    const float* __restrict__ src, unsigned short* __restrict__ dst) {
  const int t = blockIdx.x * 256 + threadIdx.x;
  const int r = t >> 7;            // 128 float4 per row
  const int c4 = (t & 127) << 2;
  const float4 v = *(const float4*)(src + (size_t)r * 512 + c4);
  ushort4 hi, lo;
  hi.x = f32_to_bf16_rne(v.x); lo.x = f32_to_bf16_rne(v.x - bf16_to_f32(hi.x));
  hi.y = f32_to_bf16_rne(v.y); lo.y = f32_to_bf16_rne(v.y - bf16_to_f32(hi.y));
  hi.z = f32_to_bf16_rne(v.z); lo.z = f32_to_bf16_rne(v.z - bf16_to_f32(hi.z));
  hi.w = f32_to_bf16_rne(v.w); lo.w = f32_to_bf16_rne(v.w - bf16_to_f32(hi.w));
  *(ushort4*)(dst + (size_t)r * 1024 + c4) = hi;
  *(ushort4*)(dst + (size_t)r * 1024 + 512 + c4) = lo;
}

// ---------------------------------------------------------------------------
// Split-bf16 MFMA GEMM, merged-term K-loop: per k0 stage A_hi, A_lo, B_hi,
// B_lo (32 KB LDS) once, then compute all 3 terms (hi@hi + lo@hi + hi@lo)
// = 48 MFMA per barrier pair (vs 16 in the term-major version -> 3x fewer
// barriers, 2/3 staging traffic, 2/3 LDS fragment reads via register reuse).
// blockIdx.z: 0 -> q (fp32 out, *1/8), 1 -> k (int16 out, *4096).
// LDS XOR swizzle (conflict-free b128 reads): chunk j of row r at j^((r>>1)&3).
// ---------------------------------------------------------------------------
__global__ __launch_bounds__(256) void gemm_mfma(
    const unsigned short* __restrict__ xs,   // [N][1024] hi|lo
    const unsigned short* __restrict__ wqs,  // [512][1024] hi|lo
    const unsigned short* __restrict__ wks,
    const float* __restrict__ q_b, const float* __restrict__ k_b,
    float* __restrict__ qout, short* __restrict__ k16) {
  __shared__ unsigned short Ah[128 * 32];
  __shared__ unsigned short Al[128 * 32];
  __shared__ unsigned short Bh[128 * 32];
  __shared__ unsigned short Bl[128 * 32];
  const int tid = threadIdx.x;
  const int w = tid >> 6;        // wave 0..3
  const int l = tid & 63;
  const bool is_q = (blockIdx.z == 0);
  const unsigned short* __restrict__ wmat = is_q ? wqs : wks;
  const float* __restrict__ bias = is_q ? q_b : k_b;

  const int bm = blockIdx.x * 128;
  const int bn = blockIdx.y * 128;
  const int wm = (w & 1) * 64;   // wave's m-quadrant
  const int wn = (w >> 1) * 64;  // wave's n-quadrant

  f32x4 acc[4][4];
#pragma unroll
  for (int i = 0; i < 4; ++i)
#pragma unroll
    for (int j = 0; j < 4; ++j) acc[i][j] = (f32x4){0.f, 0.f, 0.f, 0.f};

  // staging: lane l -> LDS (row_local = l>>2, chunk = l&3); fetch global
  // chunk (l&3) ^ ((l>>3)&3) so LDS chunk j of row r holds global chunk
  // j ^ ((r>>1)&3).
  const int sr0 = w * 16 + (l >> 2);
  const int sr1 = sr0 + 64;
  const int sc = (((l & 3) ^ ((l >> 3) & 3)) << 3);
  // fragment read: row fr = l&15, global chunk l>>4 -> LDS chunk
  // (l>>4) ^ ((fr>>1)&3)
  const int fr = l & 15;
  const int fcs = ((((l >> 4) ^ ((fr >> 1) & 3)) & 3) << 3);

  const unsigned short* __restrict__ xa = xs + (size_t)bm * 1024;
  const unsigned short* __restrict__ wa = wmat + (size_t)bn * 1024;

  for (int k0 = 0; k0 < 512; k0 += 32) {
    async16(xa + (size_t)sr0 * 1024 + k0 + sc, Ah + w * 512);
    async16(xa + (size_t)sr1 * 1024 + k0 + sc, Ah + (w + 4) * 512);
    async16(xa + (size_t)sr0 * 1024 + 512 + k0 + sc, Al + w * 512);
    async16(xa + (size_t)sr1 * 1024 + 512 + k0 + sc, Al + (w + 4) * 512);
    async16(wa + (size_t)sr0 * 1024 + k0 + sc, Bh + w * 512);
    async16(wa + (size_t)sr1 * 1024 + k0 + sc, Bh + (w + 4) * 512);
    async16(wa + (size_t)sr0 * 1024 + 512 + k0 + sc, Bl + w * 512);
    async16(wa + (size_t)sr1 * 1024 + 512 + k0 + sc, Bl + (w + 4) * 512);
    __syncthreads();

    bf16x8 ah[4], bh[4], xl[4];
#pragma unroll
    for (int i = 0; i < 4; ++i) {
      ah[i] = *(const bf16x8*)(Ah + (wm + i * 16 + fr) * 32 + fcs);
      bh[i] = *(const bf16x8*)(Bh + (wn + i * 16 + fr) * 32 + fcs);
    }
    // term 0: x_hi @ w_hi
#pragma unroll
    for (int i = 0; i < 4; ++i)
#pragma unroll
      for (int j = 0; j < 4; ++j)
        acc[i][j] = __builtin_amdgcn_mfma_f32_16x16x32_bf16(
            ah[i], bh[j], acc[i][j], 0, 0, 0);
    // term 1: x_lo @ w_hi
#pragma unroll
    for (int i = 0; i < 4; ++i)
      xl[i] = *(const bf16x8*)(Al + (wm + i * 16 + fr) * 32 + fcs);
#pragma unroll
    for (int i = 0; i < 4; ++i)
#pragma unroll
      for (int j = 0; j < 4; ++j)
        acc[i][j] = __builtin_amdgcn_mfma_f32_16x16x32_bf16(
            xl[i], bh[j], acc[i][j], 0, 0, 0);
    // term 2: x_hi @ w_lo (reuse ah; bh regs recycled for w_lo)
#pragma unroll
    for (int j = 0; j < 4; ++j)
      bh[j] = *(const bf16x8*)(Bl + (wn + j * 16 + fr) * 32 + fcs);
#pragma unroll
    for (int i = 0; i < 4; ++i)
#pragma unroll
      for (int j = 0; j < 4; ++j)
        acc[i][j] = __builtin_amdgcn_mfma_f32_16x16x32_bf16(
            ah[i], bh[j], acc[i][j], 0, 0, 0);
    __syncthreads();
  }

  // epilogue: C/D layout col = l&15 (n), row = (l>>4)*4 + reg (m)
  const int cn = l & 15;
  const int cm4 = (l >> 4) * 4;
  float bvals[4];
#pragma unroll
  for (int j = 0; j < 4; ++j) bvals[j] = bias[bn + wn + j * 16 + cn];
#pragma unroll
  for (int i = 0; i < 4; ++i) {
#pragma unroll
    for (int r = 0; r < 4; ++r) {
      const int m = bm + wm + i * 16 + cm4 + r;
      if (is_q) {
        float* op = qout + (size_t)m * 512 + bn + wn + cn;
#pragma unroll
        for (int j = 0; j < 4; ++j)
          op[j * 16] = (acc[i][j][r] + bvals[j]) * 0.125f;
      } else {
        short* op = k16 + (size_t)m * 512 + bn + wn + cn;
#pragma unroll
        for (int j = 0; j < 4; ++j) {
          float v = (acc[i][j][r] + bvals[j]) * 4096.f;
          v = fmaxf(fminf(v, 32767.f), -32767.f);
          op[j * 16] = (short)__float2int_rn(v);
        }
      }
    }
  }
}

// ---------------------------------------------------------------------------
// Fused aux: ge[e] = to_col[col_index[e]]  +  CSR row_start from sorted rows.
// ---------------------------------------------------------------------------
__global__ void build_aux(const int* __restrict__ row_index,
                          const int* __restrict__ col_index,
                          const int* __restrict__ to_col,
                          int* __restrict__ row_start,
                          int* __restrict__ ge) {
  const int e = blockIdx.x * blockDim.x + threadIdx.x;
  if (e >= NNZ_E) return;
  ge[e] = to_col[col_index[e]];
  const int r0 = row_index[e];
  const int r1 = (e + 1 < NNZ_E) ? row_index[e + 1] : N_NODES;
  if (e == 0)
    for (int r = 0; r <= r0; ++r) row_start[r] = 0;
  for (int r = r0 + 1; r <= r1; ++r) row_start[r] = e + 1;
}

// ---------------------------------------------------------------------------
// Phase A: 4 edges per wave, batched loads; k gathered as int16.
// ---------------------------------------------------------------------------
__global__ __launch_bounds__(256) void edge_logits(
    const float* __restrict__ q, const short* __restrict__ k16,
    const int* __restrict__ row_index, const int* __restrict__ ge,
    const float* __restrict__ att_bias, float* __restrict__ logits) {
  const int wave = threadIdx.x >> 6;
  const int lane = threadIdx.x & 63;
  const int e0 = __builtin_amdgcn_readfirstlane((blockIdx.x * 4 + wave) * 4);

  int r[4], g[4];
#pragma unroll
  for (int i = 0; i < 4; ++i) {
    r[i] = row_index[e0 + i];
    g[i] = ge[e0 + i];
  }

  const int lo = lane * 8;
  s16x8 kv[4];
  float4 qv[4][2];
#pragma unroll
  for (int i = 0; i < 4; ++i)
    kv[i] = *(const s16x8*)(k16 + (size_t)g[i] * E_DIM + lo);
#pragma unroll
  for (int i = 0; i < 4; ++i) {
    const float* qp = q + (size_t)r[i] * E_DIM + lo;
    qv[i][0] = *(const float4*)(qp + 0);
    qv[i][1] = *(const float4*)(qp + 4);
  }

  const int h = lane >> 3;
#pragma unroll
  for (int i = 0; i < 4; ++i) {
    float s = qv[i][0].x * (float)kv[i][0];
    s = fmaf(qv[i][0].y, (float)kv[i][1], s);
    s = fmaf(qv[i][0].z, (float)kv[i][2], s);
    s = fmaf(qv[i][0].w, (float)kv[i][3], s);
    s = fmaf(qv[i][1].x, (float)kv[i][4], s);
    s = fmaf(qv[i][1].y, (float)kv[i][5], s);
    s = fmaf(qv[i][1].z, (float)kv[i][6], s);
    s = fmaf(qv[i][1].w, (float)kv[i][7], s);
    s += __shfl_xor(s, 1);
    s += __shfl_xor(s, 2);
    s += __shfl_xor(s, 4);
    if ((lane & 7) == 0) {
      logits[(size_t)(e0 + i) * H_HEADS + h] =
          s * (1.f / 4096.f) + att_bias[(size_t)h * NNZ_E + e0 + i];
    }
  }
}

// ---------------------------------------------------------------------------
// Phase B: 4 rows per block (1 wave per row); lane (h,j) strided
// online-softmax + 3-step merge.
// ---------------------------------------------------------------------------
__global__ __launch_bounds__(256) void row_featurize(
    const float* __restrict__ logits, const int* __restrict__ row_start,
    const int* __restrict__ col_index, const float* __restrict__ dist,
    const float* __restrict__ pos, const float* __restrict__ col_pos,
    float* __restrict__ out) {
  const int r = blockIdx.x * 4 + (threadIdx.x >> 6);
  const int lane = threadIdx.x & 63;
  const int h = lane >> 3;
  const int j = lane & 7;
  const int start = row_start[r];
  const int end = row_start[r + 1];

  float m = -INFINITY, l = 0.f, accw = 0.f, a0 = 0.f, a1 = 0.f, a2 = 0.f;

  for (int e = start + j; e < end; e += 8) {
    const float s = logits[(size_t)e * H_HEADS + h];
    const float dd = dist[e];
    const float w = (dd == 0.f) ? 0.f : 1.f / dd;
    const int c = col_index[e];
    const float nm = fmaxf(m, s);
    const float sc = __expf(m - nm);
    const float p = __expf(s - nm);
    m = nm;
    l = fmaf(l, sc, p);
    const float pw = p * w;
    accw = fmaf(accw, sc, pw);
    a0 = fmaf(a0, sc, pw * col_pos[c * 3 + 0]);
    a1 = fmaf(a1, sc, pw * col_pos[c * 3 + 1]);
    a2 = fmaf(a2, sc, pw * col_pos[c * 3 + 2]);
  }

#pragma unroll
  for (int off = 1; off < 8; off <<= 1) {
    const float mo = __shfl_xor(m, off);
    const float lo = __shfl_xor(l, off);
    const float wo = __shfl_xor(accw, off);
    const float b0 = __shfl_xor(a0, off);
    const float b1 = __shfl_xor(a1, off);
    const float b2 = __shfl_xor(a2, off);
    const float nm = fmaxf(m, mo);
    const float s1 = __expf(fmaxf(m - nm, -80.f));  // NaN (inf-inf) -> -80
    const float s2 = __expf(fmaxf(mo - nm, -80.f));
    m = nm;
    l = l * s1 + lo * s2;
    accw = accw * s1 + wo * s2;
    a0 = a0 * s1 + b0 * s2;
    a1 = a1 * s1 + b1 * s2;
    a2 = a2 * s1 + b2 * s2;
  }

  if (j == 0) {
    const float invz = (l > 0.f) ? 1.f / l : 0.f;
    const float avg = accw * invz;
    const float v0 = a0 * invz - avg * pos[r * 3 + 0];
    const float v1 = a1 * invz - avg * pos[r * 3 + 1];
    const float v2 = a2 * invz - avg * pos[r * 3 + 2];
    const float nrm = sqrtf(v0 * v0 + v1 * v1 + v2 * v2);
    const float invn = 1.f / fmaxf(nrm, 1e-12f);
    float4 o;
    o.x = v0 * invn; o.y = v1 * invn; o.z = v2 * invn; o.w = avg;
    *(float4*)(out + (size_t)r * (H_HEADS * 4) + h * 4) = o;
  }
}

// ---------------------------------------------------------------------------
extern "C" void kernel_launch(void* const* d_in, const int* in_sizes, int n_in,
                              void* d_out, int out_size, void* d_ws,
                              size_t ws_size, hipStream_t stream) {
  const float* x        = (const float*)d_in[0];
  const int* row_index  = (const int*)d_in[1];
  const int* col_index  = (const int*)d_in[2];
  const int* to_col     = (const int*)d_in[3];
  const float* att_bias = (const float*)d_in[4];
  const float* dist     = (const float*)d_in[5];
  const float* pos      = (const float*)d_in[6];
  const float* col_pos  = (const float*)d_in[7];
  const float* q_w      = (const float*)d_in[8];
  const float* q_b      = (const float*)d_in[9];
  const float* k_w      = (const float*)d_in[10];
  const float* k_b      = (const float*)d_in[11];
  float* out = (float*)d_out;

  // ws: q[N*E f32] | k16[N*E s16] | xsplit[N*1024 bf16] (aliased by logits)
  //     | wq_s | wk_s | row_start[N+1] | ge[NNZ]
  float* q = (float*)d_ws;
  short* k16 = (short*)(q + (size_t)N_NODES * E_DIM);
  unsigned short* xsplit = (unsigned short*)(k16 + (size_t)N_NODES * E_DIM);
  float* logits = (float*)xsplit;  // xsplit dead after gemm_mfma
  unsigned short* wq_s = xsplit + (size_t)N_NODES * 1024;
  unsigned short* wk_s = wq_s + 512 * 1024;
  int* row_start = (int*)(wk_s + 512 * 1024);
  int* ge = row_start + (N_NODES + 1);

  cvt_split<<<N_NODES / 2, 256, 0, stream>>>(x, xsplit);
  cvt_split<<<256, 256, 0, stream>>>(q_w, wq_s);
  cvt_split<<<256, 256, 0, stream>>>(k_w, wk_s);

  dim3 gg(N_NODES / 128, E_DIM / 128, 2);
  gemm_mfma<<<gg, 256, 0, stream>>>(xsplit, wq_s, wk_s, q_b, k_b, q, k16);

  build_aux<<<NNZ_E / 256, 256, 0, stream>>>(row_index, col_index, to_col,
                                             row_start, ge);
  edge_logits<<<NNZ_E / 16, 256, 0, stream>>>(q, k16, row_index, ge,
                                              att_bias, logits);
  row_featurize<<<N_NODES / 4, 256, 0, stream>>>(logits, row_start, col_index,
                                                 dist, pos, col_pos, out);
}